// Round 9
// baseline (234.881 us; speedup 1.0000x reference)
//
#include <hip/hip_runtime.h>
#include <hip/hip_bf16.h>
#include <math.h>

// Problem constants
#define Bp 8
#define Lp 1024
#define Dp 512
#define Hp 8
#define DFCp 2048
#define ROWS (Bp*Lp)          // 8192
#define EPSp 1e-5f
#define SCALEp 0.04419417382415922f  // 1/sqrt(512)

typedef __bf16 bf16_t;
typedef __attribute__((ext_vector_type(8))) __bf16 bf16x8;
typedef __attribute__((ext_vector_type(4))) __bf16 bf16x4;
typedef __attribute__((ext_vector_type(4))) float f32x4;

// ---------------------------------------------------------------
// Fused fp32->bf16 convert of all inputs + fp32 bias pack (1 launch).
// ---------------------------------------------------------------
__global__ __launch_bounds__(256) void f2b_all(
    const float* __restrict__ x,  const float* __restrict__ Wq,
    const float* __restrict__ Wk, const float* __restrict__ Wv,
    const float* __restrict__ Wo, const float* __restrict__ c1,
    const float* __restrict__ c2,
    const float* __restrict__ bq, const float* __restrict__ bk,
    const float* __restrict__ bv,
    bf16_t* __restrict__ xb, bf16_t* __restrict__ WQKVb,
    bf16_t* __restrict__ Wob, bf16_t* __restrict__ c1b,
    bf16_t* __restrict__ c2b, float* __restrict__ bqkv)
{
    int i = blockIdx.x * 256 + threadIdx.x;
    if (i >= 1835392) return;
    if (i >= 1835008) {               // fp32 bias pack
        int j = i - 1835008;          // 0..383 quads
        const float* s; int off;
        if (j < 128)      { s = bq; off = j; }
        else if (j < 256) { s = bk; off = j - 128; }
        else              { s = bv; off = j - 256; }
        ((float4*)bqkv)[j] = ((const float4*)s)[off];
        return;
    }
    const float* src; bf16_t* dst; int off;
    if      (i < 1048576) { src = x;  dst = xb;              off = i; }
    else if (i < 1114112) { src = Wq; dst = WQKVb;           off = i - 1048576; }
    else if (i < 1179648) { src = Wk; dst = WQKVb + 262144;  off = i - 1114112; }
    else if (i < 1245184) { src = Wv; dst = WQKVb + 524288;  off = i - 1179648; }
    else if (i < 1310720) { src = Wo; dst = Wob;             off = i - 1245184; }
    else if (i < 1572864) { src = c1; dst = c1b;             off = i - 1310720; }
    else                  { src = c2; dst = c2b;             off = i - 1572864; }
    float4 v = ((const float4*)src)[off];
    bf16x4 o;
    o[0] = (bf16_t)v.x; o[1] = (bf16_t)v.y; o[2] = (bf16_t)v.z; o[3] = (bf16_t)v.w;
    ((bf16x4*)dst)[off] = o;
}

// ---------------------------------------------------------------
// bf16 MFMA GEMM, BK=64, XOR-swizzled LDS staging (unchanged R8).
// XCD-aware grid: blockIdx.x = ROW tile (A reuse), blockIdx.y = COL tile.
// ---------------------------------------------------------------
__device__ __forceinline__ void gload16(const bf16_t* g, bf16_t* l) {
    __builtin_amdgcn_global_load_lds(
        (const __attribute__((address_space(1))) void*)g,
        (__attribute__((address_space(3))) void*)l,
        16, 0, 0);
}

template<int OUT_BF16, int RELU, int SPLIT_V, int NT, int KSPLIT>
__global__ __launch_bounds__(256) void gemm_mfma(
    const bf16_t* __restrict__ A, const bf16_t* __restrict__ W,
    const float* __restrict__ bias, void* __restrict__ Cv,
    bf16_t* __restrict__ Ct, bf16_t* __restrict__ P0,
    int M, int N, int Kd)
{
    constexpr int NJ = NT / 32;          // j-frags per wave
    __shared__ bf16_t As[128 * 64];
    __shared__ bf16_t Bs[NT * 64];
    const int tid  = threadIdx.x;
    const int wave = tid >> 6;
    const int lane = tid & 63;
    const int row0 = blockIdx.x * 128;   // ROW tile on x (XCD locality)
    const int col0 = blockIdx.y * NT;    // COL tile on y
    const int wm = (wave >> 1) * 64;
    const int wn = (wave & 1) * (NT / 2);

    const int lrow   = lane >> 3;              // 0..7 row within 8-row chunk
    const int lchunk = lane & 7;               // 16B unit within row
    const int scol   = ((lchunk ^ lrow) * 8);  // swizzled col (elems)
    const int lg   = lane >> 4;                // frag k-group 0..3
    const int mrow = lane & 15;

    f32x4 acc[4][NJ] = {};

    const bf16_t* Ag = A + (size_t)row0 * Kd;
    const bf16_t* Bg = W + (size_t)col0 * Kd;

    const int Kc = Kd / KSPLIT;
    const int kbeg = (KSPLIT > 1) ? blockIdx.z * Kc : 0;

    for (int k0 = kbeg; k0 < kbeg + Kc; k0 += 64) {
        __syncthreads();
        #pragma unroll
        for (int c = 0; c < 4; ++c) {               // A: 16 chunks of 8 rows
            const int ch = c * 4 + wave;
            const int r = ch * 8 + lrow;
            gload16(Ag + (size_t)r * Kd + k0 + scol, &As[ch * 512]);
        }
        #pragma unroll
        for (int c = 0; c < NT / 32; ++c) {         // B: NT/8 chunks
            const int ch = c * 4 + wave;
            const int r = ch * 8 + lrow;
            gload16(Bg + (size_t)r * Kd + k0 + scol, &Bs[ch * 512]);
        }
        __syncthreads();

        #pragma unroll
        for (int kk = 0; kk < 2; ++kk) {
            bf16x8 af[4], bfr[NJ];
            const int lc = kk * 4 + lg;             // logical 16B chunk
            #pragma unroll
            for (int i = 0; i < 4; ++i) {
                const int r = wm + i * 16 + mrow;
                af[i] = *(const bf16x8*)&As[r * 64 + ((lc ^ (r & 7)) * 8)];
            }
            #pragma unroll
            for (int j = 0; j < NJ; ++j) {
                const int r = wn + j * 16 + mrow;
                bfr[j] = *(const bf16x8*)&Bs[r * 64 + ((lc ^ (r & 7)) * 8)];
            }
            #pragma unroll
            for (int i = 0; i < 4; ++i)
                #pragma unroll
                for (int j = 0; j < NJ; ++j)
                    acc[i][j] = __builtin_amdgcn_mfma_f32_16x16x32_bf16(
                        af[i], bfr[j], acc[i][j], 0, 0, 0);
        }
    }

    float* Cf = (float*)Cv;
    bf16_t* Cb = (bf16_t*)Cv;
    bf16_t* Pz = nullptr;
    if (KSPLIT > 1) Pz = P0 + (size_t)blockIdx.z * ((size_t)M * N);
    #pragma unroll
    for (int i = 0; i < 4; ++i) {
        const int r = row0 + wm + i * 16 + (lane >> 4) * 4;
        #pragma unroll
        for (int j = 0; j < NJ; ++j) {
            const int c = col0 + wn + j * 16 + (lane & 15);
            if (KSPLIT > 1) {
                #pragma unroll
                for (int reg = 0; reg < 4; ++reg)
                    Pz[(size_t)(r + reg) * N + c] = (bf16_t)acc[i][j][reg];
            } else if (SPLIT_V && c >= 1024) {
                const float bv = bias[c];
                const int h = (c - 1024) >> 6, d = (c - 1024) & 63;
                const int b = r >> 10, l = r & 1023;
                bf16x4 v4;
                #pragma unroll
                for (int reg = 0; reg < 4; ++reg)
                    v4[reg] = (bf16_t)(acc[i][j][reg] + bv);
                *(bf16x4*)&Ct[(((size_t)b * 8 + h) * 64 + d) * 1024 + l] = v4;
            } else {
                const float bv = bias[c];
                #pragma unroll
                for (int reg = 0; reg < 4; ++reg) {
                    float v = acc[i][j][reg] + bv;
                    if (RELU) v = fmaxf(v, 0.0f);
                    if (OUT_BF16) Cb[(size_t)(r + reg) * N + c] = (bf16_t)v;
                    else          Cf[(size_t)(r + reg) * N + c] = v;
                }
            }
        }
    }
}

// ---------------------------------------------------------------
// MFMA flash attention v3: K/V/Q staged via global_load_lds into
// UNPADDED 64x64 tiles with the GEMM's XOR chunk swizzle (measured
// zero-conflict pattern); frag reads apply the same XOR. No VGPR
// round-trip on staging. Ps keeps the padded layout (reg ds_writes).
// XCD grid: blockIdx.x = bh (K/V L2 reuse), blockIdx.y = q-tile.
// ---------------------------------------------------------------
__global__ __launch_bounds__(256) void flash_attn_mfma(
    const bf16_t* __restrict__ QKV, const bf16_t* __restrict__ Vtg,
    bf16_t* __restrict__ out)
{
    const int bh = blockIdx.x;
    const int qt = blockIdx.y;
    const int b  = bh >> 3;
    const int h  = bh & 7;
    const int tid  = threadIdx.x;
    const int wave = tid >> 6;
    const int lane = tid & 63;
    const int li = lane & 15;
    const int lg = lane >> 4;

    __shared__ bf16_t Qs[64 * 64];
    __shared__ bf16_t Ks[64 * 64];
    __shared__ bf16_t Vt[64 * 64];   // [d][s] (Vtg pre-transposed)
    __shared__ bf16_t Ps[64][72];    // [q][s], padded (regular writes)

    const size_t qrow0  = (size_t)(b * Lp + qt * 64) * 1536 + h * 64;
    const size_t krow0  = (size_t)(b * Lp) * 1536 + 512 + h * 64;
    const size_t vtbase = (size_t)bh * 64 * 1024;

    const int lrow   = lane >> 3;              // 0..7
    const int lchunk = lane & 7;               // 16B unit within 64-elem row
    const int scol   = ((lchunk ^ lrow) * 8);  // swizzled source col

    // stage Q (8 chunks of 8 rows; 4 waves x 2)
    #pragma unroll
    for (int c = 0; c < 2; ++c) {
        const int ch = c * 4 + wave;
        const int r = ch * 8 + lrow;
        gload16(&QKV[qrow0 + (size_t)r * 1536 + scol], &Qs[ch * 512]);
    }
    __syncthreads();

    bf16x8 qa0, qa1;
    {
        const int r = wave * 16 + li;
        qa0 = *(const bf16x8*)&Qs[r * 64 + ((lg ^ (r & 7)) * 8)];
        qa1 = *(const bf16x8*)&Qs[r * 64 + (((lg + 4) ^ (r & 7)) * 8)];
    }

    f32x4 O[4] = {};
    float l_lane = 0.0f;

    for (int s0 = 0; s0 < Lp; s0 += 64) {
        __syncthreads();   // prior iter done reading Ks/Vt
        #pragma unroll
        for (int c = 0; c < 2; ++c) {
            const int ch = c * 4 + wave;
            const int r = ch * 8 + lrow;
            gload16(&QKV[krow0 + (size_t)(s0 + r) * 1536 + scol], &Ks[ch * 512]);
            gload16(&Vtg[vtbase + (size_t)r * 1024 + s0 + scol], &Vt[ch * 512]);
        }
        __syncthreads();   // drains vmcnt -> tiles visible

        // S^T = K Q^T (A=K-frag, B=Q-frag); packed bf16x4 P stores
        #pragma unroll
        for (int st = 0; st < 4; ++st) {
            const int r = st * 16 + li;
            bf16x8 kf0 = *(const bf16x8*)&Ks[r * 64 + ((lg ^ (r & 7)) * 8)];
            bf16x8 kf1 = *(const bf16x8*)&Ks[r * 64 + (((lg + 4) ^ (r & 7)) * 8)];
            f32x4 z = {0.0f, 0.0f, 0.0f, 0.0f};
            z = __builtin_amdgcn_mfma_f32_16x16x32_bf16(kf0, qa0, z, 0, 0, 0);
            z = __builtin_amdgcn_mfma_f32_16x16x32_bf16(kf1, qa1, z, 0, 0, 0);
            bf16x4 p4;
            #pragma unroll
            for (int reg = 0; reg < 4; ++reg) {
                float p = __expf(z[reg] * SCALEp);
                l_lane += p;
                p4[reg] = (bf16_t)p;
            }
            *(bf16x4*)&Ps[wave * 16 + li][st * 16 + lg * 4] = p4;
        }

        // O += P V (A from own wave's Ps rows; B from swizzled Vt)
        bf16x8 pa0 = *(const bf16x8*)&Ps[wave * 16 + li][lg * 8];
        bf16x8 pa1 = *(const bf16x8*)&Ps[wave * 16 + li][32 + lg * 8];
        #pragma unroll
        for (int dt = 0; dt < 4; ++dt) {
            const int r = dt * 16 + li;
            bf16x8 vf0 = *(const bf16x8*)&Vt[r * 64 + ((lg ^ (r & 7)) * 8)];
            bf16x8 vf1 = *(const bf16x8*)&Vt[r * 64 + (((lg + 4) ^ (r & 7)) * 8)];
            O[dt] = __builtin_amdgcn_mfma_f32_16x16x32_bf16(pa0, vf0, O[dt], 0, 0, 0);
            O[dt] = __builtin_amdgcn_mfma_f32_16x16x32_bf16(pa1, vf1, O[dt], 0, 0, 0);
        }
    }

    float l_full = l_lane;
    l_full += __shfl_xor(l_full, 16);
    l_full += __shfl_xor(l_full, 32);

    #pragma unroll
    for (int reg = 0; reg < 4; ++reg) {
        const float lq = __shfl(l_full, lg * 4 + reg);
        const float inv = 1.0f / lq;
        const size_t row = (size_t)(b * Lp + qt * 64 + wave * 16 + lg * 4 + reg);
        #pragma unroll
        for (int dt = 0; dt < 4; ++dt) {
            out[row * Dp + h * 64 + dt * 16 + li] = (bf16_t)(O[dt][reg] * inv);
        }
    }
}

// ---------------------------------------------------------------
// LN1 wave-per-row (no barriers): x1b = bf16( LN(xb + xpb)*g + beta )
// Reads the bf16 shadow of x (halved fetch; ~0.002 residual error).
// ---------------------------------------------------------------
__global__ __launch_bounds__(256) void ln1_fused(
    const bf16_t* __restrict__ xb, const bf16_t* __restrict__ xpb,
    const float* __restrict__ g, const float* __restrict__ beta,
    bf16_t* __restrict__ x1b)
{
    const int wave = threadIdx.x >> 6;
    const int lane = threadIdx.x & 63;
    const int row  = blockIdx.x * 4 + wave;
    const int col  = lane * 8;
    const size_t base = (size_t)row * Dp + col;

    bf16x8 a = *(const bf16x8*)&xb[base];
    bf16x8 p = *(const bf16x8*)&xpb[base];
    float v[8];
    #pragma unroll
    for (int t = 0; t < 8; ++t) v[t] = (float)a[t] + (float)p[t];

    float s = 0.0f, q = 0.0f;
    #pragma unroll
    for (int t = 0; t < 8; ++t) { s += v[t]; q += v[t] * v[t]; }
    #pragma unroll
    for (int off = 1; off < 64; off <<= 1) {
        s += __shfl_xor(s, off);
        q += __shfl_xor(q, off);
    }
    const float mu = s * (1.0f / Dp);
    const float rstd = rsqrtf(q * (1.0f / Dp) - mu * mu + EPSp);

    float4 g0 = *(const float4*)&g[col],    g1 = *(const float4*)&g[col + 4];
    float4 b0 = *(const float4*)&beta[col], b1 = *(const float4*)&beta[col + 4];
    bf16x8 o;
    o[0] = (bf16_t)((v[0] - mu) * rstd * g0.x + b0.x);
    o[1] = (bf16_t)((v[1] - mu) * rstd * g0.y + b0.y);
    o[2] = (bf16_t)((v[2] - mu) * rstd * g0.z + b0.z);
    o[3] = (bf16_t)((v[3] - mu) * rstd * g0.w + b0.w);
    o[4] = (bf16_t)((v[4] - mu) * rstd * g1.x + b1.x);
    o[5] = (bf16_t)((v[5] - mu) * rstd * g1.y + b1.y);
    o[6] = (bf16_t)((v[6] - mu) * rstd * g1.z + b1.z);
    o[7] = (bf16_t)((v[7] - mu) * rstd * g1.w + b1.w);
    *(bf16x8*)&x1b[base] = o;
}

// ---------------------------------------------------------------
// LN2 wave-per-row with fused split-K2 reduce.
// ---------------------------------------------------------------
__global__ __launch_bounds__(256) void ln2_fused(
    const bf16_t* __restrict__ x1b, const bf16_t* __restrict__ P0,
    const float* __restrict__ bias,
    const float* __restrict__ g, const float* __restrict__ beta,
    float* __restrict__ out)
{
    const int wave = threadIdx.x >> 6;
    const int lane = threadIdx.x & 63;
    const int row  = blockIdx.x * 4 + wave;
    const int col  = lane * 8;
    const size_t base = (size_t)row * Dp + col;
    const size_t MN = (size_t)ROWS * Dp;

    bf16x8 x1 = *(const bf16x8*)&x1b[base];
    bf16x8 pa = *(const bf16x8*)&P0[base];
    bf16x8 pb = *(const bf16x8*)&P0[MN + base];
    float4 c0 = *(const float4*)&bias[col], c1 = *(const float4*)&bias[col + 4];
    const float cb[8] = { c0.x, c0.y, c0.z, c0.w, c1.x, c1.y, c1.z, c1.w };
    float v[8];
    #pragma unroll
    for (int t = 0; t < 8; ++t)
        v[t] = (float)x1[t] + (float)pa[t] + (float)pb[t] + cb[t];

    float s = 0.0f, q = 0.0f;
    #pragma unroll
    for (int t = 0; t < 8; ++t) { s += v[t]; q += v[t] * v[t]; }
    #pragma unroll
    for (int off = 1; off < 64; off <<= 1) {
        s += __shfl_xor(s, off);
        q += __shfl_xor(q, off);
    }
    const float mu = s * (1.0f / Dp);
    const float rstd = rsqrtf(q * (1.0f / Dp) - mu * mu + EPSp);

    float4 g0 = *(const float4*)&g[col],    g1 = *(const float4*)&g[col + 4];
    float4 b0 = *(const float4*)&beta[col], b1 = *(const float4*)&beta[col + 4];
    float4 o0, o1;
    o0.x = (v[0] - mu) * rstd * g0.x + b0.x;
    o0.y = (v[1] - mu) * rstd * g0.y + b0.y;
    o0.z = (v[2] - mu) * rstd * g0.z + b0.z;
    o0.w = (v[3] - mu) * rstd * g0.w + b0.w;
    o1.x = (v[4] - mu) * rstd * g1.x + b1.x;
    o1.y = (v[5] - mu) * rstd * g1.y + b1.y;
    o1.z = (v[6] - mu) * rstd * g1.z + b1.z;
    o1.w = (v[7] - mu) * rstd * g1.w + b1.w;
    *(float4*)&out[base]     = o0;
    *(float4*)&out[base + 4] = o1;
}

// ---------------------------------------------------------------
extern "C" void kernel_launch(void* const* d_in, const int* in_sizes, int n_in,
                              void* d_out, int out_size, void* d_ws, size_t ws_size,
                              hipStream_t stream)
{
    const float* x       = (const float*)d_in[0];
    const float* Wq      = (const float*)d_in[1];
    const float* bq      = (const float*)d_in[2];
    const float* Wk      = (const float*)d_in[3];
    const float* bk      = (const float*)d_in[4];
    const float* Wv      = (const float*)d_in[5];
    const float* bv      = (const float*)d_in[6];
    const float* Wo      = (const float*)d_in[7];
    const float* bo      = (const float*)d_in[8];
    const float* conv1_w = (const float*)d_in[9];
    const float* conv1_b = (const float*)d_in[10];
    const float* ln1_g   = (const float*)d_in[11];
    const float* ln1_b   = (const float*)d_in[12];
    const float* conv2_w = (const float*)d_in[13];
    const float* conv2_b = (const float*)d_in[14];
    const float* ln2_g   = (const float*)d_in[15];
    const float* ln2_b   = (const float*)d_in[16];

    // Workspace layout (bytes). Total ~82 MB.
    char* w = (char*)d_ws;
    bf16_t* QKVb = (bf16_t*)w;                       // 25165824 (V slots unused)
    bf16_t* Ab   = (bf16_t*)(w + 25165824);          //  8388608
    bf16_t* Hb   = (bf16_t*)w;                       // overlays QKVb+Ab (FFN hidden)
    char* w1     = w + 33554432;
    bf16_t* Xpb  = (bf16_t*)w1;                      //  8388608 (proj out; dead after LN1)
    bf16_t* Part0 = (bf16_t*)w1;                     // 16777216 (FFN2 partials, after LN1)
    bf16_t* X1b  = (bf16_t*)(w1 + 16777216);         //  8388608
    char* w2     = w1 + 25165824;
    bf16_t* xb     = (bf16_t*)w2;                    // 8388608
    bf16_t* WQKVb  = (bf16_t*)(w2 + 8388608);        // 1572864
    bf16_t* Wob    = (bf16_t*)(w2 + 8388608 + 1572864);          // 524288
    bf16_t* c1b    = (bf16_t*)(w2 + 8388608 + 1572864 + 524288); // 2097152
    bf16_t* c2b    = (bf16_t*)(w2 + 8388608 + 1572864 + 524288 + 2097152); // 2097152
    float*  bqkv   = (float*)(w2 + 8388608 + 1572864 + 524288 + 2*2097152); // 8192 pad
    bf16_t* Vtg    = (bf16_t*)(w2 + 8388608 + 1572864 + 524288 + 2*2097152 + 8192); // 8388608

    float* outp = (float*)d_out;
    dim3 blk(256);

    // all converts + bias pack in one launch
    hipLaunchKernelGGL(f2b_all, dim3(7170), blk, 0, stream,
                       x, Wq, Wk, Wv, Wo, conv1_w, conv2_w, bq, bk, bv,
                       xb, WQKVb, Wob, c1b, c2b, bqkv);

    // fused QKV: grid (row-tiles, col-tiles) for XCD A-locality
    hipLaunchKernelGGL((gemm_mfma<1,0,1,128,1>), dim3(ROWS/128, 1536/128), blk, 0, stream,
                       xb, WQKVb, bqkv, (void*)QKVb, Vtg, (bf16_t*)nullptr,
                       ROWS, 1536, Dp);

    // MFMA flash attention: grid (bh, q-tiles) for XCD K/V locality
    hipLaunchKernelGGL(flash_attn_mfma, dim3(Bp*Hp, Lp/64), blk, 0, stream, QKVb, Vtg, Ab);

    // proj: Xpb = bf16(Ab @ Wo^T + bo)
    hipLaunchKernelGGL((gemm_mfma<1,0,0,64,1>), dim3(ROWS/128, Dp/64), blk, 0, stream,
                       Ab, Wob, bo, (void*)Xpb, (bf16_t*)nullptr, (bf16_t*)nullptr,
                       ROWS, Dp, Dp);

    // x1b = bf16(LN(xb + Xpb))
    hipLaunchKernelGGL(ln1_fused, dim3(ROWS/4), blk, 0, stream,
                       xb, Xpb, ln1_g, ln1_b, X1b);

    // h = relu(x1 @ conv1^T + b1)
    hipLaunchKernelGGL((gemm_mfma<1,1,0,128,1>), dim3(ROWS/128, DFCp/128), blk, 0, stream,
                       X1b, c1b, conv1_b, (void*)Hb, (bf16_t*)nullptr, (bf16_t*)nullptr,
                       ROWS, DFCp, Dp);

    // y partials: split-K=2 over K=2048
    hipLaunchKernelGGL((gemm_mfma<1,0,0,64,2>), dim3(ROWS/128, Dp/64, 2), blk, 0, stream,
                       Hb, c2b, conv2_b, (void*)nullptr, (bf16_t*)nullptr, Part0,
                       ROWS, Dp, DFCp);

    // out = LN(x1 + (P[0]+P[1] + b2))
    hipLaunchKernelGGL(ln2_fused, dim3(ROWS/4), blk, 0, stream,
                       X1b, Part0, conv2_b, ln2_g, ln2_b, outp);
}

// Round 10
// 226.268 us; speedup vs baseline: 1.0381x; 1.0381x over previous
//
#include <hip/hip_runtime.h>
#include <hip/hip_bf16.h>
#include <math.h>

// Problem constants
#define Bp 8
#define Lp 1024
#define Dp 512
#define Hp 8
#define DFCp 2048
#define ROWS (Bp*Lp)          // 8192
#define EPSp 1e-5f
#define SCALEp 0.04419417382415922f  // 1/sqrt(512)

typedef __bf16 bf16_t;
typedef __attribute__((ext_vector_type(8))) __bf16 bf16x8;
typedef __attribute__((ext_vector_type(4))) __bf16 bf16x4;
typedef __attribute__((ext_vector_type(4))) float f32x4;

// ---------------------------------------------------------------
// Fused fp32->bf16 convert of all inputs + fp32 bias pack (1 launch).
// ---------------------------------------------------------------
__global__ __launch_bounds__(256) void f2b_all(
    const float* __restrict__ x,  const float* __restrict__ Wq,
    const float* __restrict__ Wk, const float* __restrict__ Wv,
    const float* __restrict__ Wo, const float* __restrict__ c1,
    const float* __restrict__ c2,
    const float* __restrict__ bq, const float* __restrict__ bk,
    const float* __restrict__ bv,
    bf16_t* __restrict__ xb, bf16_t* __restrict__ WQKVb,
    bf16_t* __restrict__ Wob, bf16_t* __restrict__ c1b,
    bf16_t* __restrict__ c2b, float* __restrict__ bqkv)
{
    int i = blockIdx.x * 256 + threadIdx.x;
    if (i >= 1835392) return;
    if (i >= 1835008) {               // fp32 bias pack
        int j = i - 1835008;          // 0..383 quads
        const float* s; int off;
        if (j < 128)      { s = bq; off = j; }
        else if (j < 256) { s = bk; off = j - 128; }
        else              { s = bv; off = j - 256; }
        ((float4*)bqkv)[j] = ((const float4*)s)[off];
        return;
    }
    const float* src; bf16_t* dst; int off;
    if      (i < 1048576) { src = x;  dst = xb;              off = i; }
    else if (i < 1114112) { src = Wq; dst = WQKVb;           off = i - 1048576; }
    else if (i < 1179648) { src = Wk; dst = WQKVb + 262144;  off = i - 1114112; }
    else if (i < 1245184) { src = Wv; dst = WQKVb + 524288;  off = i - 1179648; }
    else if (i < 1310720) { src = Wo; dst = Wob;             off = i - 1245184; }
    else if (i < 1572864) { src = c1; dst = c1b;             off = i - 1310720; }
    else                  { src = c2; dst = c2b;             off = i - 1572864; }
    float4 v = ((const float4*)src)[off];
    bf16x4 o;
    o[0] = (bf16_t)v.x; o[1] = (bf16_t)v.y; o[2] = (bf16_t)v.z; o[3] = (bf16_t)v.w;
    ((bf16x4*)dst)[off] = o;
}

// ---------------------------------------------------------------
// bf16 MFMA GEMM, BK=64, XOR-swizzled LDS staging (unchanged R8).
// XCD-aware grid: blockIdx.x = ROW tile (A reuse), blockIdx.y = COL tile.
// ---------------------------------------------------------------
__device__ __forceinline__ void gload16(const bf16_t* g, bf16_t* l) {
    __builtin_amdgcn_global_load_lds(
        (const __attribute__((address_space(1))) void*)g,
        (__attribute__((address_space(3))) void*)l,
        16, 0, 0);
}

template<int OUT_BF16, int RELU, int SPLIT_V, int NT, int KSPLIT>
__global__ __launch_bounds__(256) void gemm_mfma(
    const bf16_t* __restrict__ A, const bf16_t* __restrict__ W,
    const float* __restrict__ bias, void* __restrict__ Cv,
    bf16_t* __restrict__ Ct, bf16_t* __restrict__ P0,
    int M, int N, int Kd)
{
    constexpr int NJ = NT / 32;          // j-frags per wave
    __shared__ bf16_t As[128 * 64];
    __shared__ bf16_t Bs[NT * 64];
    const int tid  = threadIdx.x;
    const int wave = tid >> 6;
    const int lane = tid & 63;
    const int row0 = blockIdx.x * 128;   // ROW tile on x (XCD locality)
    const int col0 = blockIdx.y * NT;    // COL tile on y
    const int wm = (wave >> 1) * 64;
    const int wn = (wave & 1) * (NT / 2);

    const int lrow   = lane >> 3;              // 0..7 row within 8-row chunk
    const int lchunk = lane & 7;               // 16B unit within row
    const int scol   = ((lchunk ^ lrow) * 8);  // swizzled col (elems)
    const int lg   = lane >> 4;                // frag k-group 0..3
    const int mrow = lane & 15;

    f32x4 acc[4][NJ] = {};

    const bf16_t* Ag = A + (size_t)row0 * Kd;
    const bf16_t* Bg = W + (size_t)col0 * Kd;

    const int Kc = Kd / KSPLIT;
    const int kbeg = (KSPLIT > 1) ? blockIdx.z * Kc : 0;

    for (int k0 = kbeg; k0 < kbeg + Kc; k0 += 64) {
        __syncthreads();
        #pragma unroll
        for (int c = 0; c < 4; ++c) {               // A: 16 chunks of 8 rows
            const int ch = c * 4 + wave;
            const int r = ch * 8 + lrow;
            gload16(Ag + (size_t)r * Kd + k0 + scol, &As[ch * 512]);
        }
        #pragma unroll
        for (int c = 0; c < NT / 32; ++c) {         // B: NT/8 chunks
            const int ch = c * 4 + wave;
            const int r = ch * 8 + lrow;
            gload16(Bg + (size_t)r * Kd + k0 + scol, &Bs[ch * 512]);
        }
        __syncthreads();

        #pragma unroll
        for (int kk = 0; kk < 2; ++kk) {
            bf16x8 af[4], bfr[NJ];
            const int lc = kk * 4 + lg;             // logical 16B chunk
            #pragma unroll
            for (int i = 0; i < 4; ++i) {
                const int r = wm + i * 16 + mrow;
                af[i] = *(const bf16x8*)&As[r * 64 + ((lc ^ (r & 7)) * 8)];
            }
            #pragma unroll
            for (int j = 0; j < NJ; ++j) {
                const int r = wn + j * 16 + mrow;
                bfr[j] = *(const bf16x8*)&Bs[r * 64 + ((lc ^ (r & 7)) * 8)];
            }
            #pragma unroll
            for (int i = 0; i < 4; ++i)
                #pragma unroll
                for (int j = 0; j < NJ; ++j)
                    acc[i][j] = __builtin_amdgcn_mfma_f32_16x16x32_bf16(
                        af[i], bfr[j], acc[i][j], 0, 0, 0);
        }
    }

    float* Cf = (float*)Cv;
    bf16_t* Cb = (bf16_t*)Cv;
    bf16_t* Pz = nullptr;
    if (KSPLIT > 1) Pz = P0 + (size_t)blockIdx.z * ((size_t)M * N);
    #pragma unroll
    for (int i = 0; i < 4; ++i) {
        const int r = row0 + wm + i * 16 + (lane >> 4) * 4;
        #pragma unroll
        for (int j = 0; j < NJ; ++j) {
            const int c = col0 + wn + j * 16 + (lane & 15);
            if (KSPLIT > 1) {
                #pragma unroll
                for (int reg = 0; reg < 4; ++reg)
                    Pz[(size_t)(r + reg) * N + c] = (bf16_t)acc[i][j][reg];
            } else if (SPLIT_V && c >= 1024) {
                const float bv = bias[c];
                const int h = (c - 1024) >> 6, d = (c - 1024) & 63;
                const int b = r >> 10, l = r & 1023;
                bf16x4 v4;
                #pragma unroll
                for (int reg = 0; reg < 4; ++reg)
                    v4[reg] = (bf16_t)(acc[i][j][reg] + bv);
                *(bf16x4*)&Ct[(((size_t)b * 8 + h) * 64 + d) * 1024 + l] = v4;
            } else {
                const float bv = bias[c];
                #pragma unroll
                for (int reg = 0; reg < 4; ++reg) {
                    float v = acc[i][j][reg] + bv;
                    if (RELU) v = fmaxf(v, 0.0f);
                    if (OUT_BF16) Cb[(size_t)(r + reg) * N + c] = (bf16_t)v;
                    else          Cf[(size_t)(r + reg) * N + c] = v;
                }
            }
        }
    }
}

// ---------------------------------------------------------------
// MFMA flash attention v4: 128-query tile, 512 threads (8 waves).
// Each staged K/V tile now serves 128 q-rows (halved staging traffic
// and barrier-drains per output); per-wave work unchanged (16 q-rows).
// K/V/Q staged via global_load_lds into unpadded 64-col tiles with
// the GEMM's XOR chunk swizzle. XCD grid: blockIdx.x = bh.
// ---------------------------------------------------------------
__global__ __launch_bounds__(512) void flash_attn_mfma(
    const bf16_t* __restrict__ QKV, const bf16_t* __restrict__ Vtg,
    bf16_t* __restrict__ out)
{
    const int bh = blockIdx.x;      // 64
    const int qt = blockIdx.y;      // 8 tiles of 128 q-rows
    const int b  = bh >> 3;
    const int h  = bh & 7;
    const int tid  = threadIdx.x;
    const int wave = tid >> 6;      // 0..7
    const int lane = tid & 63;
    const int li = lane & 15;
    const int lg = lane >> 4;

    __shared__ bf16_t Qs[128 * 64];
    __shared__ bf16_t Ks[64 * 64];
    __shared__ bf16_t Vt[64 * 64];   // [d][s] (Vtg pre-transposed)
    __shared__ bf16_t Ps[128][72];   // [q][s], padded (regular writes)

    const size_t qrow0  = (size_t)(b * Lp + qt * 128) * 1536 + h * 64;
    const size_t krow0  = (size_t)(b * Lp) * 1536 + 512 + h * 64;
    const size_t vtbase = (size_t)bh * 64 * 1024;

    const int lrow   = lane >> 3;              // 0..7
    const int lchunk = lane & 7;               // 16B unit within 64-elem row
    const int scol   = ((lchunk ^ lrow) * 8);  // swizzled source col

    // stage Q: 16 chunks of 8 rows; wave handles chunks wave, wave+8
    #pragma unroll
    for (int c = 0; c < 2; ++c) {
        const int ch = c * 8 + wave;
        const int r = ch * 8 + lrow;
        gload16(&QKV[qrow0 + (size_t)r * 1536 + scol], &Qs[ch * 512]);
    }
    __syncthreads();

    bf16x8 qa0, qa1;
    {
        const int r = wave * 16 + li;
        qa0 = *(const bf16x8*)&Qs[r * 64 + ((lg ^ (r & 7)) * 8)];
        qa1 = *(const bf16x8*)&Qs[r * 64 + (((lg + 4) ^ (r & 7)) * 8)];
    }

    f32x4 O[4] = {};
    float l_lane = 0.0f;

    for (int s0 = 0; s0 < Lp; s0 += 64) {
        __syncthreads();   // prior iter done reading Ks/Vt
        {
            // K: 8 chunks, V: 8 chunks; wave w stages chunk w of each
            const int r = wave * 8 + lrow;
            gload16(&QKV[krow0 + (size_t)(s0 + r) * 1536 + scol], &Ks[wave * 512]);
            gload16(&Vtg[vtbase + (size_t)r * 1024 + s0 + scol], &Vt[wave * 512]);
        }
        __syncthreads();   // drains vmcnt -> tiles visible

        // S^T = K Q^T (A=K-frag, B=Q-frag); packed bf16x4 P stores
        #pragma unroll
        for (int st = 0; st < 4; ++st) {
            const int r = st * 16 + li;
            bf16x8 kf0 = *(const bf16x8*)&Ks[r * 64 + ((lg ^ (r & 7)) * 8)];
            bf16x8 kf1 = *(const bf16x8*)&Ks[r * 64 + (((lg + 4) ^ (r & 7)) * 8)];
            f32x4 z = {0.0f, 0.0f, 0.0f, 0.0f};
            z = __builtin_amdgcn_mfma_f32_16x16x32_bf16(kf0, qa0, z, 0, 0, 0);
            z = __builtin_amdgcn_mfma_f32_16x16x32_bf16(kf1, qa1, z, 0, 0, 0);
            bf16x4 p4;
            #pragma unroll
            for (int reg = 0; reg < 4; ++reg) {
                float p = __expf(z[reg] * SCALEp);
                l_lane += p;
                p4[reg] = (bf16_t)p;
            }
            *(bf16x4*)&Ps[wave * 16 + li][st * 16 + lg * 4] = p4;
        }

        // O += P V (A from own wave's Ps rows; B from swizzled Vt)
        bf16x8 pa0 = *(const bf16x8*)&Ps[wave * 16 + li][lg * 8];
        bf16x8 pa1 = *(const bf16x8*)&Ps[wave * 16 + li][32 + lg * 8];
        #pragma unroll
        for (int dt = 0; dt < 4; ++dt) {
            const int r = dt * 16 + li;
            bf16x8 vf0 = *(const bf16x8*)&Vt[r * 64 + ((lg ^ (r & 7)) * 8)];
            bf16x8 vf1 = *(const bf16x8*)&Vt[r * 64 + (((lg + 4) ^ (r & 7)) * 8)];
            O[dt] = __builtin_amdgcn_mfma_f32_16x16x32_bf16(pa0, vf0, O[dt], 0, 0, 0);
            O[dt] = __builtin_amdgcn_mfma_f32_16x16x32_bf16(pa1, vf1, O[dt], 0, 0, 0);
        }
    }

    float l_full = l_lane;
    l_full += __shfl_xor(l_full, 16);
    l_full += __shfl_xor(l_full, 32);

    #pragma unroll
    for (int reg = 0; reg < 4; ++reg) {
        const float lq = __shfl(l_full, lg * 4 + reg);
        const float inv = 1.0f / lq;
        const size_t row = (size_t)(b * Lp + qt * 128 + wave * 16 + lg * 4 + reg);
        #pragma unroll
        for (int dt = 0; dt < 4; ++dt) {
            out[row * Dp + h * 64 + dt * 16 + li] = (bf16_t)(O[dt][reg] * inv);
        }
    }
}

// ---------------------------------------------------------------
// LN1 wave-per-row (no barriers): x1b = bf16( LN(xb + xpb)*g + beta )
// ---------------------------------------------------------------
__global__ __launch_bounds__(256) void ln1_fused(
    const bf16_t* __restrict__ xb, const bf16_t* __restrict__ xpb,
    const float* __restrict__ g, const float* __restrict__ beta,
    bf16_t* __restrict__ x1b)
{
    const int wave = threadIdx.x >> 6;
    const int lane = threadIdx.x & 63;
    const int row  = blockIdx.x * 4 + wave;
    const int col  = lane * 8;
    const size_t base = (size_t)row * Dp + col;

    bf16x8 a = *(const bf16x8*)&xb[base];
    bf16x8 p = *(const bf16x8*)&xpb[base];
    float v[8];
    #pragma unroll
    for (int t = 0; t < 8; ++t) v[t] = (float)a[t] + (float)p[t];

    float s = 0.0f, q = 0.0f;
    #pragma unroll
    for (int t = 0; t < 8; ++t) { s += v[t]; q += v[t] * v[t]; }
    #pragma unroll
    for (int off = 1; off < 64; off <<= 1) {
        s += __shfl_xor(s, off);
        q += __shfl_xor(q, off);
    }
    const float mu = s * (1.0f / Dp);
    const float rstd = rsqrtf(q * (1.0f / Dp) - mu * mu + EPSp);

    float4 g0 = *(const float4*)&g[col],    g1 = *(const float4*)&g[col + 4];
    float4 b0 = *(const float4*)&beta[col], b1 = *(const float4*)&beta[col + 4];
    bf16x8 o;
    o[0] = (bf16_t)((v[0] - mu) * rstd * g0.x + b0.x);
    o[1] = (bf16_t)((v[1] - mu) * rstd * g0.y + b0.y);
    o[2] = (bf16_t)((v[2] - mu) * rstd * g0.z + b0.z);
    o[3] = (bf16_t)((v[3] - mu) * rstd * g0.w + b0.w);
    o[4] = (bf16_t)((v[4] - mu) * rstd * g1.x + b1.x);
    o[5] = (bf16_t)((v[5] - mu) * rstd * g1.y + b1.y);
    o[6] = (bf16_t)((v[6] - mu) * rstd * g1.z + b1.z);
    o[7] = (bf16_t)((v[7] - mu) * rstd * g1.w + b1.w);
    *(bf16x8*)&x1b[base] = o;
}

// ---------------------------------------------------------------
// LN2 wave-per-row with fused split-K2 reduce.
// ---------------------------------------------------------------
__global__ __launch_bounds__(256) void ln2_fused(
    const bf16_t* __restrict__ x1b, const bf16_t* __restrict__ P0,
    const float* __restrict__ bias,
    const float* __restrict__ g, const float* __restrict__ beta,
    float* __restrict__ out)
{
    const int wave = threadIdx.x >> 6;
    const int lane = threadIdx.x & 63;
    const int row  = blockIdx.x * 4 + wave;
    const int col  = lane * 8;
    const size_t base = (size_t)row * Dp + col;
    const size_t MN = (size_t)ROWS * Dp;

    bf16x8 x1 = *(const bf16x8*)&x1b[base];
    bf16x8 pa = *(const bf16x8*)&P0[base];
    bf16x8 pb = *(const bf16x8*)&P0[MN + base];
    float4 c0 = *(const float4*)&bias[col], c1 = *(const float4*)&bias[col + 4];
    const float cb[8] = { c0.x, c0.y, c0.z, c0.w, c1.x, c1.y, c1.z, c1.w };
    float v[8];
    #pragma unroll
    for (int t = 0; t < 8; ++t)
        v[t] = (float)x1[t] + (float)pa[t] + (float)pb[t] + cb[t];

    float s = 0.0f, q = 0.0f;
    #pragma unroll
    for (int t = 0; t < 8; ++t) { s += v[t]; q += v[t] * v[t]; }
    #pragma unroll
    for (int off = 1; off < 64; off <<= 1) {
        s += __shfl_xor(s, off);
        q += __shfl_xor(q, off);
    }
    const float mu = s * (1.0f / Dp);
    const float rstd = rsqrtf(q * (1.0f / Dp) - mu * mu + EPSp);

    float4 g0 = *(const float4*)&g[col],    g1 = *(const float4*)&g[col + 4];
    float4 b0 = *(const float4*)&beta[col], b1 = *(const float4*)&beta[col + 4];
    float4 o0, o1;
    o0.x = (v[0] - mu) * rstd * g0.x + b0.x;
    o0.y = (v[1] - mu) * rstd * g0.y + b0.y;
    o0.z = (v[2] - mu) * rstd * g0.z + b0.z;
    o0.w = (v[3] - mu) * rstd * g0.w + b0.w;
    o1.x = (v[4] - mu) * rstd * g1.x + b1.x;
    o1.y = (v[5] - mu) * rstd * g1.y + b1.y;
    o1.z = (v[6] - mu) * rstd * g1.z + b1.z;
    o1.w = (v[7] - mu) * rstd * g1.w + b1.w;
    *(float4*)&out[base]     = o0;
    *(float4*)&out[base + 4] = o1;
}

// ---------------------------------------------------------------
extern "C" void kernel_launch(void* const* d_in, const int* in_sizes, int n_in,
                              void* d_out, int out_size, void* d_ws, size_t ws_size,
                              hipStream_t stream)
{
    const float* x       = (const float*)d_in[0];
    const float* Wq      = (const float*)d_in[1];
    const float* bq      = (const float*)d_in[2];
    const float* Wk      = (const float*)d_in[3];
    const float* bk      = (const float*)d_in[4];
    const float* Wv      = (const float*)d_in[5];
    const float* bv      = (const float*)d_in[6];
    const float* Wo      = (const float*)d_in[7];
    const float* bo      = (const float*)d_in[8];
    const float* conv1_w = (const float*)d_in[9];
    const float* conv1_b = (const float*)d_in[10];
    const float* ln1_g   = (const float*)d_in[11];
    const float* ln1_b   = (const float*)d_in[12];
    const float* conv2_w = (const float*)d_in[13];
    const float* conv2_b = (const float*)d_in[14];
    const float* ln2_g   = (const float*)d_in[15];
    const float* ln2_b   = (const float*)d_in[16];

    // Workspace layout (bytes). Total ~82 MB.
    char* w = (char*)d_ws;
    bf16_t* QKVb = (bf16_t*)w;                       // 25165824 (V slots unused)
    bf16_t* Ab   = (bf16_t*)(w + 25165824);          //  8388608
    bf16_t* Hb   = (bf16_t*)w;                       // overlays QKVb+Ab (FFN hidden)
    char* w1     = w + 33554432;
    bf16_t* Xpb  = (bf16_t*)w1;                      //  8388608 (proj out; dead after LN1)
    bf16_t* Part0 = (bf16_t*)w1;                     // 16777216 (FFN2 partials, after LN1)
    bf16_t* X1b  = (bf16_t*)(w1 + 16777216);         //  8388608
    char* w2     = w1 + 25165824;
    bf16_t* xb     = (bf16_t*)w2;                    // 8388608
    bf16_t* WQKVb  = (bf16_t*)(w2 + 8388608);        // 1572864
    bf16_t* Wob    = (bf16_t*)(w2 + 8388608 + 1572864);          // 524288
    bf16_t* c1b    = (bf16_t*)(w2 + 8388608 + 1572864 + 524288); // 2097152
    bf16_t* c2b    = (bf16_t*)(w2 + 8388608 + 1572864 + 524288 + 2097152); // 2097152
    float*  bqkv   = (float*)(w2 + 8388608 + 1572864 + 524288 + 2*2097152); // 8192 pad
    bf16_t* Vtg    = (bf16_t*)(w2 + 8388608 + 1572864 + 524288 + 2*2097152 + 8192); // 8388608

    float* outp = (float*)d_out;
    dim3 blk(256);

    // all converts + bias pack in one launch
    hipLaunchKernelGGL(f2b_all, dim3(7170), blk, 0, stream,
                       x, Wq, Wk, Wv, Wo, conv1_w, conv2_w, bq, bk, bv,
                       xb, WQKVb, Wob, c1b, c2b, bqkv);

    // fused QKV: grid (row-tiles, col-tiles) for XCD A-locality
    hipLaunchKernelGGL((gemm_mfma<1,0,1,128,1>), dim3(ROWS/128, 1536/128), blk, 0, stream,
                       xb, WQKVb, bqkv, (void*)QKVb, Vtg, (bf16_t*)nullptr,
                       ROWS, 1536, Dp);

    // MFMA flash attention: 128-q tiles, 512 threads, grid (bh, q-tiles)
    hipLaunchKernelGGL(flash_attn_mfma, dim3(Bp*Hp, Lp/128), dim3(512), 0, stream,
                       QKVb, Vtg, Ab);

    // proj: Xpb = bf16(Ab @ Wo^T + bo)
    hipLaunchKernelGGL((gemm_mfma<1,0,0,64,1>), dim3(ROWS/128, Dp/64), blk, 0, stream,
                       Ab, Wob, bo, (void*)Xpb, (bf16_t*)nullptr, (bf16_t*)nullptr,
                       ROWS, Dp, Dp);

    // x1b = bf16(LN(xb + Xpb))
    hipLaunchKernelGGL(ln1_fused, dim3(ROWS/4), blk, 0, stream,
                       xb, Xpb, ln1_g, ln1_b, X1b);

    // h = relu(x1 @ conv1^T + b1)
    hipLaunchKernelGGL((gemm_mfma<1,1,0,128,1>), dim3(ROWS/128, DFCp/128), blk, 0, stream,
                       X1b, c1b, conv1_b, (void*)Hb, (bf16_t*)nullptr, (bf16_t*)nullptr,
                       ROWS, DFCp, Dp);

    // y partials: split-K=2 over K=2048
    hipLaunchKernelGGL((gemm_mfma<1,0,0,64,2>), dim3(ROWS/128, Dp/64, 2), blk, 0, stream,
                       Hb, c2b, conv2_b, (void*)nullptr, (bf16_t*)nullptr, Part0,
                       ROWS, Dp, DFCp);

    // out = LN(x1 + (P[0]+P[1] + b2))
    hipLaunchKernelGGL(ln2_fused, dim3(ROWS/4), blk, 0, stream,
                       X1b, Part0, conv2_b, ln2_g, ln2_b, outp);
}

// Round 12
// 217.389 us; speedup vs baseline: 1.0805x; 1.0408x over previous
//
#include <hip/hip_runtime.h>
#include <hip/hip_bf16.h>
#include <math.h>

// Problem constants
#define Bp 8
#define Lp 1024
#define Dp 512
#define Hp 8
#define DFCp 2048
#define ROWS (Bp*Lp)          // 8192
#define EPSp 1e-5f
#define SCALEp 0.04419417382415922f  // 1/sqrt(512)

typedef __bf16 bf16_t;
typedef __attribute__((ext_vector_type(8))) __bf16 bf16x8;
typedef __attribute__((ext_vector_type(4))) __bf16 bf16x4;
typedef __attribute__((ext_vector_type(4))) float f32x4;

// ---------------------------------------------------------------
// Fused fp32->bf16 convert of all inputs + fp32 bias pack (1 launch).
// ---------------------------------------------------------------
__global__ __launch_bounds__(256) void f2b_all(
    const float* __restrict__ x,  const float* __restrict__ Wq,
    const float* __restrict__ Wk, const float* __restrict__ Wv,
    const float* __restrict__ Wo, const float* __restrict__ c1,
    const float* __restrict__ c2,
    const float* __restrict__ bq, const float* __restrict__ bk,
    const float* __restrict__ bv,
    bf16_t* __restrict__ xb, bf16_t* __restrict__ WQKVb,
    bf16_t* __restrict__ Wob, bf16_t* __restrict__ c1b,
    bf16_t* __restrict__ c2b, float* __restrict__ bqkv)
{
    int i = blockIdx.x * 256 + threadIdx.x;
    if (i >= 1835392) return;
    if (i >= 1835008) {               // fp32 bias pack
        int j = i - 1835008;          // 0..383 quads
        const float* s; int off;
        if (j < 128)      { s = bq; off = j; }
        else if (j < 256) { s = bk; off = j - 128; }
        else              { s = bv; off = j - 256; }
        ((float4*)bqkv)[j] = ((const float4*)s)[off];
        return;
    }
    const float* src; bf16_t* dst; int off;
    if      (i < 1048576) { src = x;  dst = xb;              off = i; }
    else if (i < 1114112) { src = Wq; dst = WQKVb;           off = i - 1048576; }
    else if (i < 1179648) { src = Wk; dst = WQKVb + 262144;  off = i - 1114112; }
    else if (i < 1245184) { src = Wv; dst = WQKVb + 524288;  off = i - 1179648; }
    else if (i < 1310720) { src = Wo; dst = Wob;             off = i - 1245184; }
    else if (i < 1572864) { src = c1; dst = c1b;             off = i - 1310720; }
    else                  { src = c2; dst = c2b;             off = i - 1572864; }
    float4 v = ((const float4*)src)[off];
    bf16x4 o;
    o[0] = (bf16_t)v.x; o[1] = (bf16_t)v.y; o[2] = (bf16_t)v.z; o[3] = (bf16_t)v.w;
    ((bf16x4*)dst)[off] = o;
}

// ---------------------------------------------------------------
// bf16 MFMA GEMM, BK=64, XOR-swizzled LDS staging.
// XCD-aware grid: blockIdx.x = ROW tile (A reuse), blockIdx.y = COL tile.
// ---------------------------------------------------------------
__device__ __forceinline__ void gload16(const bf16_t* g, bf16_t* l) {
    __builtin_amdgcn_global_load_lds(
        (const __attribute__((address_space(1))) void*)g,
        (__attribute__((address_space(3))) void*)l,
        16, 0, 0);
}

template<int OUT_BF16, int RELU, int SPLIT_V, int NT, int KSPLIT>
__global__ __launch_bounds__(256) void gemm_mfma(
    const bf16_t* __restrict__ A, const bf16_t* __restrict__ W,
    const float* __restrict__ bias, void* __restrict__ Cv,
    bf16_t* __restrict__ Ct, bf16_t* __restrict__ P0,
    int M, int N, int Kd)
{
    constexpr int NJ = NT / 32;          // j-frags per wave
    __shared__ bf16_t As[128 * 64];
    __shared__ bf16_t Bs[NT * 64];
    const int tid  = threadIdx.x;
    const int wave = tid >> 6;
    const int lane = tid & 63;
    const int row0 = blockIdx.x * 128;   // ROW tile on x (XCD locality)
    const int col0 = blockIdx.y * NT;    // COL tile on y
    const int wm = (wave >> 1) * 64;
    const int wn = (wave & 1) * (NT / 2);

    const int lrow   = lane >> 3;              // 0..7 row within 8-row chunk
    const int lchunk = lane & 7;               // 16B unit within row
    const int scol   = ((lchunk ^ lrow) * 8);  // swizzled col (elems)
    const int lg   = lane >> 4;                // frag k-group 0..3
    const int mrow = lane & 15;

    f32x4 acc[4][NJ] = {};

    const bf16_t* Ag = A + (size_t)row0 * Kd;
    const bf16_t* Bg = W + (size_t)col0 * Kd;

    const int Kc = Kd / KSPLIT;
    const int kbeg = (KSPLIT > 1) ? blockIdx.z * Kc : 0;

    for (int k0 = kbeg; k0 < kbeg + Kc; k0 += 64) {
        __syncthreads();
        #pragma unroll
        for (int c = 0; c < 4; ++c) {               // A: 16 chunks of 8 rows
            const int ch = c * 4 + wave;
            const int r = ch * 8 + lrow;
            gload16(Ag + (size_t)r * Kd + k0 + scol, &As[ch * 512]);
        }
        #pragma unroll
        for (int c = 0; c < NT / 32; ++c) {         // B: NT/8 chunks
            const int ch = c * 4 + wave;
            const int r = ch * 8 + lrow;
            gload16(Bg + (size_t)r * Kd + k0 + scol, &Bs[ch * 512]);
        }
        __syncthreads();

        #pragma unroll
        for (int kk = 0; kk < 2; ++kk) {
            bf16x8 af[4], bfr[NJ];
            const int lc = kk * 4 + lg;             // logical 16B chunk
            #pragma unroll
            for (int i = 0; i < 4; ++i) {
                const int r = wm + i * 16 + mrow;
                af[i] = *(const bf16x8*)&As[r * 64 + ((lc ^ (r & 7)) * 8)];
            }
            #pragma unroll
            for (int j = 0; j < NJ; ++j) {
                const int r = wn + j * 16 + mrow;
                bfr[j] = *(const bf16x8*)&Bs[r * 64 + ((lc ^ (r & 7)) * 8)];
            }
            #pragma unroll
            for (int i = 0; i < 4; ++i)
                #pragma unroll
                for (int j = 0; j < NJ; ++j)
                    acc[i][j] = __builtin_amdgcn_mfma_f32_16x16x32_bf16(
                        af[i], bfr[j], acc[i][j], 0, 0, 0);
        }
    }

    float* Cf = (float*)Cv;
    bf16_t* Cb = (bf16_t*)Cv;
    bf16_t* Pz = nullptr;
    if (KSPLIT > 1) Pz = P0 + (size_t)blockIdx.z * ((size_t)M * N);
    #pragma unroll
    for (int i = 0; i < 4; ++i) {
        const int r = row0 + wm + i * 16 + (lane >> 4) * 4;
        #pragma unroll
        for (int j = 0; j < NJ; ++j) {
            const int c = col0 + wn + j * 16 + (lane & 15);
            if (KSPLIT > 1) {
                #pragma unroll
                for (int reg = 0; reg < 4; ++reg)
                    Pz[(size_t)(r + reg) * N + c] = (bf16_t)acc[i][j][reg];
            } else if (SPLIT_V && c >= 1024) {
                const float bv = bias[c];
                const int h = (c - 1024) >> 6, d = (c - 1024) & 63;
                const int b = r >> 10, l = r & 1023;
                bf16x4 v4;
                #pragma unroll
                for (int reg = 0; reg < 4; ++reg)
                    v4[reg] = (bf16_t)(acc[i][j][reg] + bv);
                *(bf16x4*)&Ct[(((size_t)b * 8 + h) * 64 + d) * 1024 + l] = v4;
            } else {
                const float bv = bias[c];
                #pragma unroll
                for (int reg = 0; reg < 4; ++reg) {
                    float v = acc[i][j][reg] + bv;
                    if (RELU) v = fmaxf(v, 0.0f);
                    if (OUT_BF16) Cb[(size_t)(r + reg) * N + c] = (bf16_t)v;
                    else          Cf[(size_t)(r + reg) * N + c] = v;
                }
            }
        }
    }
}

// ---------------------------------------------------------------
// MFMA flash attention v4 (R10 measured-good): 128-query tile,
// 512 threads (8 waves). Each staged K/V tile serves 128 q-rows.
// K/V/Q staged via global_load_lds into unpadded 64-col tiles with
// the GEMM's XOR chunk swizzle. XCD grid: blockIdx.x = bh.
// ---------------------------------------------------------------
__global__ __launch_bounds__(512) void flash_attn_mfma(
    const bf16_t* __restrict__ QKV, const bf16_t* __restrict__ Vtg,
    bf16_t* __restrict__ out)
{
    const int bh = blockIdx.x;      // 64
    const int qt = blockIdx.y;      // 8 tiles of 128 q-rows
    const int b  = bh >> 3;
    const int h  = bh & 7;
    const int tid  = threadIdx.x;
    const int wave = tid >> 6;      // 0..7
    const int lane = tid & 63;
    const int li = lane & 15;
    const int lg = lane >> 4;

    __shared__ bf16_t Qs[128 * 64];
    __shared__ bf16_t Ks[64 * 64];
    __shared__ bf16_t Vt[64 * 64];   // [d][s] (Vtg pre-transposed)
    __shared__ bf16_t Ps[128][72];   // [q][s], padded (regular writes)

    const size_t qrow0  = (size_t)(b * Lp + qt * 128) * 1536 + h * 64;
    const size_t krow0  = (size_t)(b * Lp) * 1536 + 512 + h * 64;
    const size_t vtbase = (size_t)bh * 64 * 1024;

    const int lrow   = lane >> 3;              // 0..7
    const int lchunk = lane & 7;               // 16B unit within 64-elem row
    const int scol   = ((lchunk ^ lrow) * 8);  // swizzled source col

    // stage Q: 16 chunks of 8 rows; wave handles chunks wave, wave+8
    #pragma unroll
    for (int c = 0; c < 2; ++c) {
        const int ch = c * 8 + wave;
        const int r = ch * 8 + lrow;
        gload16(&QKV[qrow0 + (size_t)r * 1536 + scol], &Qs[ch * 512]);
    }
    __syncthreads();

    bf16x8 qa0, qa1;
    {
        const int r = wave * 16 + li;
        qa0 = *(const bf16x8*)&Qs[r * 64 + ((lg ^ (r & 7)) * 8)];
        qa1 = *(const bf16x8*)&Qs[r * 64 + (((lg + 4) ^ (r & 7)) * 8)];
    }

    f32x4 O[4] = {};
    float l_lane = 0.0f;

    for (int s0 = 0; s0 < Lp; s0 += 64) {
        __syncthreads();   // prior iter done reading Ks/Vt
        {
            // K: 8 chunks, V: 8 chunks; wave w stages chunk w of each
            const int r = wave * 8 + lrow;
            gload16(&QKV[krow0 + (size_t)(s0 + r) * 1536 + scol], &Ks[wave * 512]);
            gload16(&Vtg[vtbase + (size_t)r * 1024 + s0 + scol], &Vt[wave * 512]);
        }
        __syncthreads();   // drains vmcnt -> tiles visible

        // S^T = K Q^T (A=K-frag, B=Q-frag); packed bf16x4 P stores
        #pragma unroll
        for (int st = 0; st < 4; ++st) {
            const int r = st * 16 + li;
            bf16x8 kf0 = *(const bf16x8*)&Ks[r * 64 + ((lg ^ (r & 7)) * 8)];
            bf16x8 kf1 = *(const bf16x8*)&Ks[r * 64 + (((lg + 4) ^ (r & 7)) * 8)];
            f32x4 z = {0.0f, 0.0f, 0.0f, 0.0f};
            z = __builtin_amdgcn_mfma_f32_16x16x32_bf16(kf0, qa0, z, 0, 0, 0);
            z = __builtin_amdgcn_mfma_f32_16x16x32_bf16(kf1, qa1, z, 0, 0, 0);
            bf16x4 p4;
            #pragma unroll
            for (int reg = 0; reg < 4; ++reg) {
                float p = __expf(z[reg] * SCALEp);
                l_lane += p;
                p4[reg] = (bf16_t)p;
            }
            *(bf16x4*)&Ps[wave * 16 + li][st * 16 + lg * 4] = p4;
        }

        // O += P V (A from own wave's Ps rows; B from swizzled Vt)
        bf16x8 pa0 = *(const bf16x8*)&Ps[wave * 16 + li][lg * 8];
        bf16x8 pa1 = *(const bf16x8*)&Ps[wave * 16 + li][32 + lg * 8];
        #pragma unroll
        for (int dt = 0; dt < 4; ++dt) {
            const int r = dt * 16 + li;
            bf16x8 vf0 = *(const bf16x8*)&Vt[r * 64 + ((lg ^ (r & 7)) * 8)];
            bf16x8 vf1 = *(const bf16x8*)&Vt[r * 64 + (((lg + 4) ^ (r & 7)) * 8)];
            O[dt] = __builtin_amdgcn_mfma_f32_16x16x32_bf16(pa0, vf0, O[dt], 0, 0, 0);
            O[dt] = __builtin_amdgcn_mfma_f32_16x16x32_bf16(pa1, vf1, O[dt], 0, 0, 0);
        }
    }

    float l_full = l_lane;
    l_full += __shfl_xor(l_full, 16);
    l_full += __shfl_xor(l_full, 32);

    #pragma unroll
    for (int reg = 0; reg < 4; ++reg) {
        const float lq = __shfl(l_full, lg * 4 + reg);
        const float inv = 1.0f / lq;
        const size_t row = (size_t)(b * Lp + qt * 128 + wave * 16 + lg * 4 + reg);
        #pragma unroll
        for (int dt = 0; dt < 4; ++dt) {
            out[row * Dp + h * 64 + dt * 16 + li] = (bf16_t)(O[dt][reg] * inv);
        }
    }
}

// ---------------------------------------------------------------
// LN1 wave-per-row (no barriers): x1b = bf16( LN(xb + xpb)*g + beta )
// ---------------------------------------------------------------
__global__ __launch_bounds__(256) void ln1_fused(
    const bf16_t* __restrict__ xb, const bf16_t* __restrict__ xpb,
    const float* __restrict__ g, const float* __restrict__ beta,
    bf16_t* __restrict__ x1b)
{
    const int wave = threadIdx.x >> 6;
    const int lane = threadIdx.x & 63;
    const int row  = blockIdx.x * 4 + wave;
    const int col  = lane * 8;
    const size_t base = (size_t)row * Dp + col;

    bf16x8 a = *(const bf16x8*)&xb[base];
    bf16x8 p = *(const bf16x8*)&xpb[base];
    float v[8];
    #pragma unroll
    for (int t = 0; t < 8; ++t) v[t] = (float)a[t] + (float)p[t];

    float s = 0.0f, q = 0.0f;
    #pragma unroll
    for (int t = 0; t < 8; ++t) { s += v[t]; q += v[t] * v[t]; }
    #pragma unroll
    for (int off = 1; off < 64; off <<= 1) {
        s += __shfl_xor(s, off);
        q += __shfl_xor(q, off);
    }
    const float mu = s * (1.0f / Dp);
    const float rstd = rsqrtf(q * (1.0f / Dp) - mu * mu + EPSp);

    float4 g0 = *(const float4*)&g[col],    g1 = *(const float4*)&g[col + 4];
    float4 b0 = *(const float4*)&beta[col], b1 = *(const float4*)&beta[col + 4];
    bf16x8 o;
    o[0] = (bf16_t)((v[0] - mu) * rstd * g0.x + b0.x);
    o[1] = (bf16_t)((v[1] - mu) * rstd * g0.y + b0.y);
    o[2] = (bf16_t)((v[2] - mu) * rstd * g0.z + b0.z);
    o[3] = (bf16_t)((v[3] - mu) * rstd * g0.w + b0.w);
    o[4] = (bf16_t)((v[4] - mu) * rstd * g1.x + b1.x);
    o[5] = (bf16_t)((v[5] - mu) * rstd * g1.y + b1.y);
    o[6] = (bf16_t)((v[6] - mu) * rstd * g1.z + b1.z);
    o[7] = (bf16_t)((v[7] - mu) * rstd * g1.w + b1.w);
    *(bf16x8*)&x1b[base] = o;
}

// ---------------------------------------------------------------
// LN2 wave-per-row with fused split-K2 reduce.
// ---------------------------------------------------------------
__global__ __launch_bounds__(256) void ln2_fused(
    const bf16_t* __restrict__ x1b, const bf16_t* __restrict__ P0,
    const float* __restrict__ bias,
    const float* __restrict__ g, const float* __restrict__ beta,
    float* __restrict__ out)
{
    const int wave = threadIdx.x >> 6;
    const int lane = threadIdx.x & 63;
    const int row  = blockIdx.x * 4 + wave;
    const int col  = lane * 8;
    const size_t base = (size_t)row * Dp + col;
    const size_t MN = (size_t)ROWS * Dp;

    bf16x8 x1 = *(const bf16x8*)&x1b[base];
    bf16x8 pa = *(const bf16x8*)&P0[base];
    bf16x8 pb = *(const bf16x8*)&P0[MN + base];
    float4 c0 = *(const float4*)&bias[col], c1 = *(const float4*)&bias[col + 4];
    const float cb[8] = { c0.x, c0.y, c0.z, c0.w, c1.x, c1.y, c1.z, c1.w };
    float v[8];
    #pragma unroll
    for (int t = 0; t < 8; ++t)
        v[t] = (float)x1[t] + (float)pa[t] + (float)pb[t] + cb[t];

    float s = 0.0f, q = 0.0f;
    #pragma unroll
    for (int t = 0; t < 8; ++t) { s += v[t]; q += v[t] * v[t]; }
    #pragma unroll
    for (int off = 1; off < 64; off <<= 1) {
        s += __shfl_xor(s, off);
        q += __shfl_xor(q, off);
    }
    const float mu = s * (1.0f / Dp);
    const float rstd = rsqrtf(q * (1.0f / Dp) - mu * mu + EPSp);

    float4 g0 = *(const float4*)&g[col],    g1 = *(const float4*)&g[col + 4];
    float4 b0 = *(const float4*)&beta[col], b1 = *(const float4*)&beta[col + 4];
    float4 o0, o1;
    o0.x = (v[0] - mu) * rstd * g0.x + b0.x;
    o0.y = (v[1] - mu) * rstd * g0.y + b0.y;
    o0.z = (v[2] - mu) * rstd * g0.z + b0.z;
    o0.w = (v[3] - mu) * rstd * g0.w + b0.w;
    o1.x = (v[4] - mu) * rstd * g1.x + b1.x;
    o1.y = (v[5] - mu) * rstd * g1.y + b1.y;
    o1.z = (v[6] - mu) * rstd * g1.z + b1.z;
    o1.w = (v[7] - mu) * rstd * g1.w + b1.w;
    *(float4*)&out[base]     = o0;
    *(float4*)&out[base + 4] = o1;
}

// ---------------------------------------------------------------
extern "C" void kernel_launch(void* const* d_in, const int* in_sizes, int n_in,
                              void* d_out, int out_size, void* d_ws, size_t ws_size,
                              hipStream_t stream)
{
    const float* x       = (const float*)d_in[0];
    const float* Wq      = (const float*)d_in[1];
    const float* bq      = (const float*)d_in[2];
    const float* Wk      = (const float*)d_in[3];
    const float* bk      = (const float*)d_in[4];
    const float* Wv      = (const float*)d_in[5];
    const float* bv      = (const float*)d_in[6];
    const float* Wo      = (const float*)d_in[7];
    const float* bo      = (const float*)d_in[8];
    const float* conv1_w = (const float*)d_in[9];
    const float* conv1_b = (const float*)d_in[10];
    const float* ln1_g   = (const float*)d_in[11];
    const float* ln1_b   = (const float*)d_in[12];
    const float* conv2_w = (const float*)d_in[13];
    const float* conv2_b = (const float*)d_in[14];
    const float* ln2_g   = (const float*)d_in[15];
    const float* ln2_b   = (const float*)d_in[16];

    // Workspace layout (bytes). Total ~82 MB.
    char* w = (char*)d_ws;
    bf16_t* QKVb = (bf16_t*)w;                       // 25165824 (V slots unused)
    bf16_t* Ab   = (bf16_t*)(w + 25165824);          //  8388608
    bf16_t* Hb   = (bf16_t*)w;                       // overlays QKVb+Ab (FFN hidden)
    char* w1     = w + 33554432;
    bf16_t* Xpb  = (bf16_t*)w1;                      //  8388608 (proj out; dead after LN1)
    bf16_t* Part0 = (bf16_t*)w1;                     // 16777216 (FFN2 partials, after LN1)
    bf16_t* X1b  = (bf16_t*)(w1 + 16777216);         //  8388608
    char* w2     = w1 + 25165824;
    bf16_t* xb     = (bf16_t*)w2;                    // 8388608
    bf16_t* WQKVb  = (bf16_t*)(w2 + 8388608);        // 1572864
    bf16_t* Wob    = (bf16_t*)(w2 + 8388608 + 1572864);          // 524288
    bf16_t* c1b    = (bf16_t*)(w2 + 8388608 + 1572864 + 524288); // 2097152
    bf16_t* c2b    = (bf16_t*)(w2 + 8388608 + 1572864 + 524288 + 2097152); // 2097152
    float*  bqkv   = (float*)(w2 + 8388608 + 1572864 + 524288 + 2*2097152); // 8192 pad
    bf16_t* Vtg    = (bf16_t*)(w2 + 8388608 + 1572864 + 524288 + 2*2097152 + 8192); // 8388608

    float* outp = (float*)d_out;
    dim3 blk(256);

    // all converts + bias pack in one launch
    hipLaunchKernelGGL(f2b_all, dim3(7170), blk, 0, stream,
                       x, Wq, Wk, Wv, Wo, conv1_w, conv2_w, bq, bk, bv,
                       xb, WQKVb, Wob, c1b, c2b, bqkv);

    // fused QKV: grid (row-tiles, col-tiles) for XCD A-locality
    hipLaunchKernelGGL((gemm_mfma<1,0,1,128,1>), dim3(ROWS/128, 1536/128), blk, 0, stream,
                       xb, WQKVb, bqkv, (void*)QKVb, Vtg, (bf16_t*)nullptr,
                       ROWS, 1536, Dp);

    // MFMA flash attention: 128-q tiles, 512 threads, grid (bh, q-tiles)
    hipLaunchKernelGGL(flash_attn_mfma, dim3(Bp*Hp, Lp/128), dim3(512), 0, stream,
                       QKVb, Vtg, Ab);

    // proj: Xpb = bf16(Ab @ Wo^T + bo)
    hipLaunchKernelGGL((gemm_mfma<1,0,0,64,1>), dim3(ROWS/128, Dp/64), blk, 0, stream,
                       Ab, Wob, bo, (void*)Xpb, (bf16_t*)nullptr, (bf16_t*)nullptr,
                       ROWS, Dp, Dp);

    // x1b = bf16(LN(xb + Xpb))
    hipLaunchKernelGGL(ln1_fused, dim3(ROWS/4), blk, 0, stream,
                       xb, Xpb, ln1_g, ln1_b, X1b);

    // h = relu(x1 @ conv1^T + b1)
    hipLaunchKernelGGL((gemm_mfma<1,1,0,128,1>), dim3(ROWS/128, DFCp/128), blk, 0, stream,
                       X1b, c1b, conv1_b, (void*)Hb, (bf16_t*)nullptr, (bf16_t*)nullptr,
                       ROWS, DFCp, Dp);

    // y partials: split-K=2 over K=2048
    hipLaunchKernelGGL((gemm_mfma<1,0,0,64,2>), dim3(ROWS/128, Dp/64, 2), blk, 0, stream,
                       Hb, c2b, conv2_b, (void*)nullptr, (bf16_t*)nullptr, Part0,
                       ROWS, Dp, DFCp);

    // out = LN(x1 + (P[0]+P[1] + b2))
    hipLaunchKernelGGL(ln2_fused, dim3(ROWS/4), blk, 0, stream,
                       X1b, Part0, conv2_b, ln2_g, ln2_b, outp);
}